// Round 6
// baseline (493.236 us; speedup 1.0000x reference)
//
#include <hip/hip_runtime.h>
#include <math.h>

// StatisticalFeatureLoss — R11: pipelined pass-2 ("PP") for K=7.
// R10 post-mortem: VGPR stuck ~100 (mn/msq lifetime 3R+1 -> rings are
// structural), 4 waves is a fact; VALUBusy 74% => ~26% all-waves lgkm
// stall from TWO dependent bperm round-trips per iteration. PP defers
// pass-2 one iteration: iter i consumes bperm(xcm_{i-1}) (full iter of
// slack) and issues bperm(xcm_i) at the end; pass-1 taps are consumed
// after pass-2's ~200 VALU cycles. skew/kurt denominators carried one
// iter (denS/denK) so mn/msq lifetime stays 3R+1. K=3/K=5: proven R5
// configs (R10's K5 D=8 variant regressed; reverted).

static constexpr int H = 512, W = 512, PLANES = 48;
static constexpr float EPSF = 1e-8f;

__global__ void init_acc_kernel(double* acc) {
    if (threadIdx.x < 4) acc[threadIdx.x] = 0.0;
}

__global__ void final_kernel(const double* __restrict__ acc, float* __restrict__ out) {
    if (threadIdx.x == 0) {
        const double npix = (double)PLANES * H * W;
        double tot = acc[0] + acc[1] + 0.5 * acc[2] + 0.001 * acc[3];
        out[0] = (float)(tot / (npix * 12.0));
    }
}

__device__ __forceinline__ float bperm(int addr, float v) {
    return __int_as_float(__builtin_amdgcn_ds_bpermute(addr, __float_as_int(v)));
}

// ---- non-pipelined iteration (proven R5/R10 body) ----
#define STAT_ITER(I_, U_)                                                      \
  {                                                                            \
    const int ii = (I_);                                                       \
    const int uu = (U_);                                                       \
    const int yrow = y0 + ii;                                                  \
    const float rmask = (((unsigned)(yrow - R) < (unsigned)H) ? 1.f : 0.f) * colmask; \
    _Pragma("unroll")                                                          \
    for (int s = 0; s < 2; ++s) {                                              \
      const float x = pfbuf[s][uu % P];                                        \
      pfbuf[s][uu % P] = loadrow(s, yrow + P);                                 \
      xr[s][uu % DX] = x;                                                      \
      float w[K];                                                              \
      _Pragma("unroll")                                                        \
      for (int j = 0; j < K; ++j) w[j] = (j == R) ? x : bperm(adrb + 4 * j, x); \
      float hx = 0.f, hq = 0.f;                                                \
      _Pragma("unroll")                                                        \
      for (int j = 0; j < K; ++j) { hx += g[j] * w[j]; hq += g[j] * (w[j] * w[j]); } \
      _Pragma("unroll")                                                        \
      for (int d = 0; d < K; ++d) {                                            \
        const int sl = (uu + d - R + 2 * D) % D;                               \
        if (d == K - 1) { mn[s][sl] = g[d] * hx; msq[s][sl] = g[d] * hq; }     \
        else           { mn[s][sl] += g[d] * hx; msq[s][sl] += g[d] * hq; }    \
      }                                                                        \
      const float xold  = xr[s][(uu - R + 2 * DX) % DX];                       \
      const float mean1 = mn[s][(uu - R + 2 * D) % D];                         \
      const float xcm   = (xold - mean1) * rmask;                              \
      float wc[K];                                                             \
      _Pragma("unroll")                                                        \
      for (int j = 0; j < K; ++j) wc[j] = (j == R) ? xcm : bperm(adrb + 4 * j, xcm); \
      float v3 = 0.f, v4 = 0.f;                                                \
      _Pragma("unroll")                                                        \
      for (int j = 0; j < K; ++j) {                                            \
        const float c2 = wc[j] * wc[j];                                        \
        v3 += g[j] * (c2 * wc[j]);                                             \
        v4 += g[j] * (c2 * c2);                                                \
      }                                                                        \
      _Pragma("unroll")                                                        \
      for (int d = 0; d < K; ++d) {                                            \
        const int sl = (uu + d - 2 * R + 2 * D) % D;                           \
        if (d == K - 1) { m3a[s][sl] = g[d] * v3; m4a[s][sl] = g[d] * v4; }    \
        else           { m3a[s][sl] += g[d] * v3; m4a[s][sl] += g[d] * v4; }   \
      }                                                                        \
      if (ii >= 4 * R && ii < T) {                                             \
        const int se = (uu - 2 * R + 2 * D) % D;                               \
        const float mean = mn[s][se];                                          \
        const float var  = fmaxf(msq[s][se] - mean * mean, EPSF);              \
        const float sd   = sqrtf(var);                                         \
        const float skew = __fdividef(m3a[s][se], sd * var + EPSF);            \
        const float kurt = __fdividef(m4a[s][se], var * var + EPSF);           \
        if (s == 0) {                                                          \
          featp[0] = mean; featp[1] = var; featp[2] = skew; featp[3] = kurt;   \
        } else {                                                               \
          sums[0] += fabsf(featp[0] - mean);                                   \
          sums[1] += fabsf(featp[1] - var);                                    \
          sums[2] += fabsf(featp[2] - skew);                                   \
          sums[3] += fabsf(featp[3] - kurt);                                   \
        }                                                                      \
      }                                                                        \
    }                                                                          \
  }

// ---- pipelined iteration: pass-2 runs one iteration behind pass-1 ----
// Phase A: issue pass-1 taps (both tensors).  Phase B: consume LAST iter's
// xcm taps (wcp), scatter m3/m4 (row base ii-1), sk-emit row ii-2R-1 using
// denS/denK carried from last iter's mv-emit.  Phase C: consume pass-1
// taps, scatter mn/msq, mv-emit row ii-2R (computes denS/denK), compute
// xcm_i, issue its taps into wcp for the next iteration.
#define STAT_ITER_PP(I_, U_)                                                   \
  {                                                                            \
    const int ii = (I_);                                                       \
    const int uu = (U_);                                                       \
    const int yrow = y0 + ii;                                                  \
    const float rmask = (((unsigned)(yrow - R) < (unsigned)H) ? 1.f : 0.f) * colmask; \
    float w[2][K];                                                             \
    _Pragma("unroll")                                                          \
    for (int s = 0; s < 2; ++s) {                                              \
      const float xa = pfbuf[s][uu % P];                                       \
      pfbuf[s][uu % P] = loadrow(s, yrow + P);                                 \
      xr[s][uu % DX] = xa;                                                     \
      _Pragma("unroll")                                                        \
      for (int j = 0; j < K; ++j) w[s][j] = (j == R) ? xa : bperm(adrb + 4 * j, xa); \
    }                                                                          \
    _Pragma("unroll")                                                          \
    for (int s = 0; s < 2; ++s) {                                              \
      float v3 = 0.f, v4 = 0.f;                                                \
      _Pragma("unroll")                                                        \
      for (int j = 0; j < K; ++j) {                                            \
        const float c2 = wcp[s][j] * wcp[s][j];                                \
        v3 += g[j] * (c2 * wcp[s][j]);                                         \
        v4 += g[j] * (c2 * c2);                                                \
      }                                                                        \
      _Pragma("unroll")                                                        \
      for (int d = 0; d < K; ++d) {                                            \
        const int sl = (uu - 1 + d - 2 * R + 3 * D) % D;                       \
        if (d == K - 1) { m3a[s][sl] = g[d] * v3; m4a[s][sl] = g[d] * v4; }    \
        else           { m3a[s][sl] += g[d] * v3; m4a[s][sl] += g[d] * v4; }   \
      }                                                                        \
      if (ii >= 4 * R + 1 && ii <= T) {                                        \
        const int sesk = (uu - 1 - 2 * R + 3 * D) % D;                         \
        const float skew = __fdividef(m3a[s][sesk], denS[s]);                  \
        const float kurt = __fdividef(m4a[s][sesk], denK[s]);                  \
        if (s == 0) { fsk0 = skew; fsk1 = kurt; }                              \
        else { sums[2] += fabsf(fsk0 - skew); sums[3] += fabsf(fsk1 - kurt); } \
      }                                                                        \
    }                                                                          \
    _Pragma("unroll")                                                          \
    for (int s = 0; s < 2; ++s) {                                              \
      float hx = 0.f, hq = 0.f;                                                \
      _Pragma("unroll")                                                        \
      for (int j = 0; j < K; ++j) { hx += g[j] * w[s][j]; hq += g[j] * (w[s][j] * w[s][j]); } \
      _Pragma("unroll")                                                        \
      for (int d = 0; d < K; ++d) {                                            \
        const int sl = (uu + d - R + 2 * D) % D;                               \
        if (d == K - 1) { mn[s][sl] = g[d] * hx; msq[s][sl] = g[d] * hq; }     \
        else           { mn[s][sl] += g[d] * hx; msq[s][sl] += g[d] * hq; }    \
      }                                                                        \
      if (ii >= 4 * R && ii < T) {                                             \
        const int se = (uu - 2 * R + 2 * D) % D;                               \
        const float mean = mn[s][se];                                          \
        const float var  = fmaxf(msq[s][se] - mean * mean, EPSF);              \
        const float sd   = sqrtf(var);                                         \
        denS[s] = sd * var + EPSF;                                             \
        denK[s] = var * var + EPSF;                                            \
        if (s == 0) { fmv0 = mean; fmv1 = var; }                               \
        else { sums[0] += fabsf(fmv0 - mean); sums[1] += fabsf(fmv1 - var); }  \
      }                                                                        \
      const float xold  = xr[s][(uu - R + 2 * DX) % DX];                       \
      const float mean1 = mn[s][(uu - R + 2 * D) % D];                         \
      const float xcm   = (xold - mean1) * rmask;                              \
      _Pragma("unroll")                                                        \
      for (int j = 0; j < K; ++j) wcp[s][j] = (j == R) ? xcm : bperm(adrb + 4 * j, xcm); \
    }                                                                          \
  }

template <int K, int BAND, int D, int DX, int P, int NSTRIP, int PIPE>
__global__ __launch_bounds__(256)
void stat_kernel(const float* __restrict__ pred, const float* __restrict__ targ,
                 double* __restrict__ acc) {
    constexpr int R  = K / 2;
    constexpr int OW = 64 - 4 * R;            // valid output cols per strip
    constexpr int NBAND = H / BAND;
    constexpr int T  = BAND + 4 * R;          // real iterations
    constexpr int Tp = ((T + D - 1 + PIPE) / D) * D; // padded (PP needs iter T)
    static_assert(D % P == 0 && D % DX == 0, "index folding needs P|D, DX|D");
    static_assert(D >= 3 * R + 1 && DX > R, "ring lifetimes");

    const int wv    = threadIdx.x >> 6;       // wave within block
    const int wid   = blockIdx.x * 4 + wv;    // global wave id
    const int band  = wid % NBAND;
    const int tmp   = wid / NBAND;
    const int strip = tmp % NSTRIP;
    const int plane = tmp / NSTRIP;
    const int t     = threadIdx.x & 63;       // lane
    const int gc0   = strip * OW - 2 * R + t; // this lane's global col
    const int y0    = band * BAND - 2 * R;

    const bool  iva     = (unsigned)gc0 < (unsigned)W;
    const float colmask = iva ? 1.f : 0.f;
    const float emask   = (t >= 2 * R && t < 2 * R + OW && gc0 < W) ? 1.f : 0.f;

    // Single bpermute base; +4*j folds into the DS offset: immediate.
    // Lane wrap for halo lanes is contained (excluded by emask), as proven.
    const int adrb = (t - R) << 2;

    // Gaussian weights (reference numerics), lane-uniform
    float g[K];
    {
        const float sigma = (float)K / 6.0f;
        const float inv2s2 = 1.0f / (2.0f * sigma * sigma);
        float s = 0.0f;
#pragma unroll
        for (int i = 0; i < K; ++i) {
            float c = (float)(i - K / 2);
            g[i] = expf(-c * c * inv2s2);
            s += g[i];
        }
#pragma unroll
        for (int i = 0; i < K; ++i)
            g[i] = __int_as_float(__builtin_amdgcn_readfirstlane(__float_as_int(g[i] / s)));
    }

    // 32-bit saddr-form addressing (SGPR base + 32-bit element index)
    const unsigned ibase = (unsigned)(plane * (H * W) + gc0);

    auto loadrow = [&](int s, int y) -> float {
        float v = 0.f;
        if (iva && (unsigned)y < (unsigned)H)
            v = (s == 0 ? pred : targ)[ibase + ((unsigned)y << 9)];
        return v;
    };

    // Rotating accumulators (constant-indexed after the D-unroll)
    float mn[2][D], msq[2][D], m3a[2][D], m4a[2][D], xr[2][DX];
    float pfbuf[2][P];                        // deep prefetch ring
    float featp[4];                           // non-PP emit staging
    float wcp[2][K] = {};                     // PP: xcm taps issued last iter
    float denS[2] = {1.f, 1.f}, denK[2] = {1.f, 1.f};  // PP: carried denominators
    float fsk0 = 0.f, fsk1 = 0.f, fmv0 = 0.f, fmv1 = 0.f;
    float sums[4] = {0.f, 0.f, 0.f, 0.f};

#pragma unroll
    for (int j = 0; j < P; ++j) {             // warmup: rows y0 .. y0+P-1
        pfbuf[0][j] = loadrow(0, y0 + j);
        pfbuf[1][j] = loadrow(1, y0 + j);
    }

    for (int yy = 0; yy < Tp; yy += D) {
#pragma unroll
        for (int u = 0; u < D; ++u) {
            if constexpr (PIPE) { STAT_ITER_PP(yy + u, u) }
            else                { STAT_ITER(yy + u, u) }
        }
    }

    // per-wave reduction, then one cross-wave LDS pass, 4 atomics per block
    __shared__ float red[4][4];   // [wave][feature]
#pragma unroll
    for (int f = 0; f < 4; ++f) {
        float v = sums[f] * emask;
#pragma unroll
        for (int off = 32; off > 0; off >>= 1) v += __shfl_down(v, off, 64);
        if (t == 0) red[wv][f] = v;
    }
    __syncthreads();
    if (threadIdx.x < 4) {
        float v = red[0][threadIdx.x] + red[1][threadIdx.x]
                + red[2][threadIdx.x] + red[3][threadIdx.x];
        atomicAdd(&acc[threadIdx.x], (double)v);
    }
}

extern "C" void kernel_launch(void* const* d_in, const int* in_sizes, int n_in,
                              void* d_out, int out_size, void* d_ws, size_t ws_size,
                              hipStream_t stream) {
    const float* pred = (const float*)d_in[0];
    const float* targ = (const float*)d_in[1];
    double* acc = (double*)d_ws;
    float* out = (float*)d_out;

    init_acc_kernel<<<1, 64, 0, stream>>>(acc);

    // K, BAND, D, DX(|D, >R), P(|D), NSTRIP, PIPE; 4 waves/block
    // K=3/K=5: proven R5 configs. K=7: BAND=32 grid + pipelined pass-2.
    stat_kernel<3, 32,  4, 2, 4,  9, 0><<<dim3(PLANES *  9 * 16 / 4), 256, 0, stream>>>(pred, targ, acc);
    stat_kernel<5, 32,  7, 7, 7, 10, 0><<<dim3(PLANES * 10 * 16 / 4), 256, 0, stream>>>(pred, targ, acc);
    stat_kernel<7, 32, 10, 5, 5, 10, 1><<<dim3(PLANES * 10 * 16 / 4), 256, 0, stream>>>(pred, targ, acc);

    final_kernel<<<1, 64, 0, stream>>>(acc, out);
}

// Round 7
// 451.393 us; speedup vs baseline: 1.0927x; 1.0927x over previous
//
#include <hip/hip_runtime.h>
#include <math.h>

// StatisticalFeatureLoss — R12: recombination of measured-best pieces.
// R11 post-mortem: PP regressed (VGPR 128, more moves, no stall cut).
// Key insight from 6 rounds + m69: occupancy steps at VGPR 64/128/256 —
// 96 vs 104 is THE SAME residency (4 waves/SIMD). So: R8's K=7 tail-split
// (measured 188us) was good; its K=5 regression was the tail DUPLICATION
// on K=5 (not occupancy); R10's K=5 regression was P 7->4 (prefetch depth).
// R12: per-K configs — K7: BAND=32 + tail-split + P=10 (VGPR headroom is
// free to 124; deeper vmcnt slack); K5: exact R5 (D=7,DX=7,P=7, padded);
// K3: unchanged. No forcing, no new structure.

static constexpr int H = 512, W = 512, PLANES = 48;
static constexpr float EPSF = 1e-8f;

__global__ void init_acc_kernel(double* acc) {
    if (threadIdx.x < 4) acc[threadIdx.x] = 0.0;
}

__global__ void final_kernel(const double* __restrict__ acc, float* __restrict__ out) {
    if (threadIdx.x == 0) {
        const double npix = (double)PLANES * H * W;
        double tot = acc[0] + acc[1] + 0.5 * acc[2] + 0.001 * acc[3];
        out[0] = (float)(tot / (npix * 12.0));
    }
}

__device__ __forceinline__ float bperm(int addr, float v) {
    return __int_as_float(__builtin_amdgcn_ds_bpermute(addr, __float_as_int(v)));
}

// One pipeline iteration (proven R5/R10 body). Call sites guarantee
// (I_) % D == (U_) with (U_) literal-foldable, so ring indices fold to
// constants. Internal names ii/uu never collide with call-site vars.
#define STAT_ITER(I_, U_)                                                      \
  {                                                                            \
    const int ii = (I_);                                                       \
    const int uu = (U_);                                                       \
    const int yrow = y0 + ii;                                                  \
    const float rmask = (((unsigned)(yrow - R) < (unsigned)H) ? 1.f : 0.f) * colmask; \
    _Pragma("unroll")                                                          \
    for (int s = 0; s < 2; ++s) {                                              \
      const float x = pfbuf[s][uu % P];                                        \
      pfbuf[s][uu % P] = loadrow(s, yrow + P);                                 \
      xr[s][uu % DX] = x;                                                      \
      float w[K];                                                              \
      _Pragma("unroll")                                                        \
      for (int j = 0; j < K; ++j) w[j] = (j == R) ? x : bperm(adrb + 4 * j, x); \
      float hx = 0.f, hq = 0.f;                                                \
      _Pragma("unroll")                                                        \
      for (int j = 0; j < K; ++j) { hx += g[j] * w[j]; hq += g[j] * (w[j] * w[j]); } \
      _Pragma("unroll")                                                        \
      for (int d = 0; d < K; ++d) {                                            \
        const int sl = (uu + d - R + 2 * D) % D;                               \
        if (d == K - 1) { mn[s][sl] = g[d] * hx; msq[s][sl] = g[d] * hq; }     \
        else           { mn[s][sl] += g[d] * hx; msq[s][sl] += g[d] * hq; }    \
      }                                                                        \
      const float xold  = xr[s][(uu - R + 2 * DX) % DX];                       \
      const float mean1 = mn[s][(uu - R + 2 * D) % D];                         \
      const float xcm   = (xold - mean1) * rmask;                              \
      float wc[K];                                                             \
      _Pragma("unroll")                                                        \
      for (int j = 0; j < K; ++j) wc[j] = (j == R) ? xcm : bperm(adrb + 4 * j, xcm); \
      float v3 = 0.f, v4 = 0.f;                                                \
      _Pragma("unroll")                                                        \
      for (int j = 0; j < K; ++j) {                                            \
        const float c2 = wc[j] * wc[j];                                        \
        v3 += g[j] * (c2 * wc[j]);                                             \
        v4 += g[j] * (c2 * c2);                                                \
      }                                                                        \
      _Pragma("unroll")                                                        \
      for (int d = 0; d < K; ++d) {                                            \
        const int sl = (uu + d - 2 * R + 2 * D) % D;                           \
        if (d == K - 1) { m3a[s][sl] = g[d] * v3; m4a[s][sl] = g[d] * v4; }    \
        else           { m3a[s][sl] += g[d] * v3; m4a[s][sl] += g[d] * v4; }   \
      }                                                                        \
      if (ii >= 4 * R && ii < T) {                                             \
        const int se = (uu - 2 * R + 2 * D) % D;                               \
        const float mean = mn[s][se];                                          \
        const float var  = fmaxf(msq[s][se] - mean * mean, EPSF);              \
        const float sd   = sqrtf(var);                                         \
        const float skew = __fdividef(m3a[s][se], sd * var + EPSF);            \
        const float kurt = __fdividef(m4a[s][se], var * var + EPSF);           \
        if (s == 0) {                                                          \
          featp[0] = mean; featp[1] = var; featp[2] = skew; featp[3] = kurt;   \
        } else {                                                               \
          sums[0] += fabsf(featp[0] - mean);                                   \
          sums[1] += fabsf(featp[1] - var);                                    \
          sums[2] += fabsf(featp[2] - skew);                                   \
          sums[3] += fabsf(featp[3] - kurt);                                   \
        }                                                                      \
      }                                                                        \
    }                                                                          \
  }

template <int K, int BAND, int D, int DX, int P, int NSTRIP, int TAILSPLIT>
__global__ __launch_bounds__(256)
void stat_kernel(const float* __restrict__ pred, const float* __restrict__ targ,
                 double* __restrict__ acc) {
    constexpr int R  = K / 2;
    constexpr int OW = 64 - 4 * R;            // valid output cols per strip
    constexpr int NBAND = H / BAND;
    constexpr int T  = BAND + 4 * R;          // real iterations
    constexpr int Tp = ((T + D - 1) / D) * D; // padded count (non-tail path)
    constexpr int TMAIN = (T / D) * D;        // tail path: full-unroll part
    constexpr int TTAIL = T - TMAIN;          // tail path: exact remainder
    static_assert(D % P == 0 && D % DX == 0, "index folding needs P|D, DX|D");
    static_assert(D >= 3 * R + 1 && DX > R, "ring lifetimes");

    const int wv    = threadIdx.x >> 6;       // wave within block
    const int wid   = blockIdx.x * 4 + wv;    // global wave id
    const int band  = wid % NBAND;
    const int tmp   = wid / NBAND;
    const int strip = tmp % NSTRIP;
    const int plane = tmp / NSTRIP;
    const int t     = threadIdx.x & 63;       // lane
    const int gc0   = strip * OW - 2 * R + t; // this lane's global col
    const int y0    = band * BAND - 2 * R;

    const bool  iva     = (unsigned)gc0 < (unsigned)W;
    const float colmask = iva ? 1.f : 0.f;
    const float emask   = (t >= 2 * R && t < 2 * R + OW && gc0 < W) ? 1.f : 0.f;

    // Single bpermute base; +4*j folds into the DS offset: immediate.
    // Halo-lane wrap is contained (those lanes excluded by emask).
    const int adrb = (t - R) << 2;

    // Gaussian weights (reference numerics), lane-uniform in SGPRs
    float g[K];
    {
        const float sigma = (float)K / 6.0f;
        const float inv2s2 = 1.0f / (2.0f * sigma * sigma);
        float s = 0.0f;
#pragma unroll
        for (int i = 0; i < K; ++i) {
            float c = (float)(i - K / 2);
            g[i] = expf(-c * c * inv2s2);
            s += g[i];
        }
#pragma unroll
        for (int i = 0; i < K; ++i)
            g[i] = __int_as_float(__builtin_amdgcn_readfirstlane(__float_as_int(g[i] / s)));
    }

    // 32-bit saddr-form addressing (SGPR base + 32-bit element index)
    const unsigned ibase = (unsigned)(plane * (H * W) + gc0);

    auto loadrow = [&](int s, int y) -> float {
        float v = 0.f;
        if (iva && (unsigned)y < (unsigned)H)
            v = (s == 0 ? pred : targ)[ibase + ((unsigned)y << 9)];
        return v;
    };

    // Rotating accumulators (constant-indexed after the D-unroll)
    float mn[2][D], msq[2][D], m3a[2][D], m4a[2][D], xr[2][DX];
    float pfbuf[2][P];                        // deep prefetch ring
    float featp[4];
    float sums[4] = {0.f, 0.f, 0.f, 0.f};

#pragma unroll
    for (int j = 0; j < P; ++j) {             // warmup: rows y0 .. y0+P-1
        pfbuf[0][j] = loadrow(0, y0 + j);
        pfbuf[1][j] = loadrow(1, y0 + j);
    }

    if constexpr (TAILSPLIT) {
        for (int yy = 0; yy < TMAIN; yy += D) {
#pragma unroll
            for (int u = 0; u < D; ++u) {
                STAT_ITER(yy + u, u)          // i % D == u (D | yy)
            }
        }
        if constexpr (TTAIL > 0) {
#pragma unroll
            for (int u = 0; u < TTAIL; ++u) {
                STAT_ITER(TMAIN + u, u)       // TMAIN % D == 0
            }
        }
    } else {
        for (int yy = 0; yy < Tp; yy += D) {
#pragma unroll
            for (int u = 0; u < D; ++u) {
                STAT_ITER(yy + u, u)
            }
        }
    }

    // per-wave reduction, then one cross-wave LDS pass, 4 atomics per block
    __shared__ float red[4][4];   // [wave][feature]
#pragma unroll
    for (int f = 0; f < 4; ++f) {
        float v = sums[f] * emask;
#pragma unroll
        for (int off = 32; off > 0; off >>= 1) v += __shfl_down(v, off, 64);
        if (t == 0) red[wv][f] = v;
    }
    __syncthreads();
    if (threadIdx.x < 4) {
        float v = red[0][threadIdx.x] + red[1][threadIdx.x]
                + red[2][threadIdx.x] + red[3][threadIdx.x];
        atomicAdd(&acc[threadIdx.x], (double)v);
    }
}

extern "C" void kernel_launch(void* const* d_in, const int* in_sizes, int n_in,
                              void* d_out, int out_size, void* d_ws, size_t ws_size,
                              hipStream_t stream) {
    const float* pred = (const float*)d_in[0];
    const float* targ = (const float*)d_in[1];
    double* acc = (double*)d_ws;
    float* out = (float*)d_out;

    init_acc_kernel<<<1, 64, 0, stream>>>(acc);

    // K, BAND, D, DX(|D, >R), P(|D), NSTRIP, TAILSPLIT; 4 waves/block
    // K=3: T=36, D=4 -> exact either way; padded path.
    // K=5: exact R5 config (D=7, DX=7, P=7; Tp=42, 2 dead iters) — the
    //      tail-split variant (TTAIL=5) duplicated the body and regressed (R8).
    // K=7: BAND=32, T=44, D=10, tail-split (TTAIL=4; R8 measured 188us),
    //      P=10 deep prefetch (VGPR headroom to 124 is occupancy-free).
    stat_kernel<3, 32,  4, 2,  4,  9, 0><<<dim3(PLANES *  9 * 16 / 4), 256, 0, stream>>>(pred, targ, acc);
    stat_kernel<5, 32,  7, 7,  7, 10, 0><<<dim3(PLANES * 10 * 16 / 4), 256, 0, stream>>>(pred, targ, acc);
    stat_kernel<7, 32, 10, 5, 10, 10, 1><<<dim3(PLANES * 10 * 16 / 4), 256, 0, stream>>>(pred, targ, acc);

    final_kernel<<<1, 64, 0, stream>>>(acc, out);
}

// Round 8
// 450.371 us; speedup vs baseline: 1.0952x; 1.0023x over previous
//
#include <hip/hip_runtime.h>
#include <math.h>

// StatisticalFeatureLoss — R13: recombination, zero new ideas.
// Attribution table over R5..R12 (rest = total - K7 time):
//   R5  K7~210 rest~227  (adr[K] + 64-bit ptrs)
//   R10 K7~210 rest~253  (adrb + ibase)          <- "free shavings" cost ~30us
//   R12 K7~192 rest~259  (adrb + ibase, K5=R5 cfg) -> R10's K5-config blame was WRONG
// So: restore R5's addressing (adr[K] array, per-lane 64-bit src pointers)
// everywhere. K=7 keeps R8's measured-188 config: BAND=32, D=10, P=5,
// tail-split (TAILSPLIT=1 for K=7 ONLY — R8 applied it to all K and the
// body duplication regressed K=5). K=3/K=5: literal R5 configs.
// VGPR 100-104 is occupancy-equivalent (steps at 64/128/256).

static constexpr int H = 512, W = 512, PLANES = 48;
static constexpr float EPSF = 1e-8f;

__global__ void init_acc_kernel(double* acc) {
    if (threadIdx.x < 4) acc[threadIdx.x] = 0.0;
}

__global__ void final_kernel(const double* __restrict__ acc, float* __restrict__ out) {
    if (threadIdx.x == 0) {
        const double npix = (double)PLANES * H * W;
        double tot = acc[0] + acc[1] + 0.5 * acc[2] + 0.001 * acc[3];
        out[0] = (float)(tot / (npix * 12.0));
    }
}

__device__ __forceinline__ float bperm(int addr, float v) {
    return __int_as_float(__builtin_amdgcn_ds_bpermute(addr, __float_as_int(v)));
}

// One pipeline iteration (R5's proven body, ii/uu-safe names). Call sites
// guarantee (I_) % D == (U_) with (U_) literal-foldable, so ring indices
// fold to constants and the arrays stay in registers.
#define STAT_ITER(I_, U_)                                                      \
  {                                                                            \
    const int ii = (I_);                                                       \
    const int uu = (U_);                                                       \
    const int yrow = y0 + ii;                                                  \
    const float rmask = (((unsigned)(yrow - R) < (unsigned)H) ? 1.f : 0.f) * colmask; \
    _Pragma("unroll")                                                          \
    for (int s = 0; s < 2; ++s) {                                              \
      const float x = pfbuf[s][uu % P];                                        \
      pfbuf[s][uu % P] = loadrow(s, yrow + P);                                 \
      xr[s][uu % DX] = x;                                                      \
      float w[K];                                                              \
      _Pragma("unroll")                                                        \
      for (int j = 0; j < K; ++j) w[j] = (j == R) ? x : bperm(adr[j], x);      \
      float hx = 0.f, hq = 0.f;                                                \
      _Pragma("unroll")                                                        \
      for (int j = 0; j < K; ++j) { hx += g[j] * w[j]; hq += g[j] * (w[j] * w[j]); } \
      _Pragma("unroll")                                                        \
      for (int d = 0; d < K; ++d) {                                            \
        const int sl = (uu + d - R + 2 * D) % D;                               \
        if (d == K - 1) { mn[s][sl] = g[d] * hx; msq[s][sl] = g[d] * hq; }     \
        else           { mn[s][sl] += g[d] * hx; msq[s][sl] += g[d] * hq; }    \
      }                                                                        \
      const float xold  = xr[s][(uu - R + 2 * DX) % DX];                       \
      const float mean1 = mn[s][(uu - R + 2 * D) % D];                         \
      const float xcm   = (xold - mean1) * rmask;                              \
      float wc[K];                                                             \
      _Pragma("unroll")                                                        \
      for (int j = 0; j < K; ++j) wc[j] = (j == R) ? xcm : bperm(adr[j], xcm); \
      float v3 = 0.f, v4 = 0.f;                                                \
      _Pragma("unroll")                                                        \
      for (int j = 0; j < K; ++j) {                                            \
        const float c2 = wc[j] * wc[j];                                        \
        v3 += g[j] * (c2 * wc[j]);                                             \
        v4 += g[j] * (c2 * c2);                                                \
      }                                                                        \
      _Pragma("unroll")                                                        \
      for (int d = 0; d < K; ++d) {                                            \
        const int sl = (uu + d - 2 * R + 2 * D) % D;                           \
        if (d == K - 1) { m3a[s][sl] = g[d] * v3; m4a[s][sl] = g[d] * v4; }    \
        else           { m3a[s][sl] += g[d] * v3; m4a[s][sl] += g[d] * v4; }   \
      }                                                                        \
      if (ii >= 4 * R && ii < T) {                                             \
        const int se = (uu - 2 * R + 2 * D) % D;                               \
        const float mean = mn[s][se];                                          \
        const float var  = fmaxf(msq[s][se] - mean * mean, EPSF);              \
        const float sd   = sqrtf(var);                                         \
        const float skew = __fdividef(m3a[s][se], sd * var + EPSF);            \
        const float kurt = __fdividef(m4a[s][se], var * var + EPSF);           \
        if (s == 0) {                                                          \
          featp[0] = mean; featp[1] = var; featp[2] = skew; featp[3] = kurt;   \
        } else {                                                               \
          sums[0] += fabsf(featp[0] - mean);                                   \
          sums[1] += fabsf(featp[1] - var);                                    \
          sums[2] += fabsf(featp[2] - skew);                                   \
          sums[3] += fabsf(featp[3] - kurt);                                   \
        }                                                                      \
      }                                                                        \
    }                                                                          \
  }

template <int K, int BAND, int D, int DX, int P, int NSTRIP, int TAILSPLIT>
__global__ __launch_bounds__(256)
void stat_kernel(const float* __restrict__ pred, const float* __restrict__ targ,
                 double* __restrict__ acc) {
    constexpr int R  = K / 2;
    constexpr int OW = 64 - 4 * R;            // valid output cols per strip
    constexpr int NBAND = H / BAND;
    constexpr int T  = BAND + 4 * R;          // real iterations
    constexpr int Tp = ((T + D - 1) / D) * D; // padded count (non-tail path)
    constexpr int TMAIN = (T / D) * D;        // tail path: full-unroll part
    constexpr int TTAIL = T - TMAIN;          // tail path: exact remainder
    static_assert(D % P == 0 && D % DX == 0, "index folding needs P|D, DX|D");
    static_assert(D >= 3 * R + 1 && DX > R, "ring lifetimes");

    const int wv    = threadIdx.x >> 6;       // wave within block
    const int wid   = blockIdx.x * 4 + wv;    // global wave id
    const int band  = wid % NBAND;
    const int tmp   = wid / NBAND;
    const int strip = tmp % NSTRIP;
    const int plane = tmp / NSTRIP;
    const int t     = threadIdx.x & 63;       // lane
    const int gc0   = strip * OW - 2 * R + t; // this lane's global col
    const int y0    = band * BAND - 2 * R;

    const bool  iva     = (unsigned)gc0 < (unsigned)W;
    const float colmask = iva ? 1.f : 0.f;
    const float emask   = (t >= 2 * R && t < 2 * R + OW && gc0 < W) ? 1.f : 0.f;

    int adr[K];   // ds_bpermute lane byte-addresses (wave-relative) — R5 form
#pragma unroll
    for (int j = 0; j < K; ++j) adr[j] = (t - R + j) << 2;

    // Gaussian weights (reference numerics), lane-uniform in SGPRs
    float g[K];
    {
        const float sigma = (float)K / 6.0f;
        const float inv2s2 = 1.0f / (2.0f * sigma * sigma);
        float s = 0.0f;
#pragma unroll
        for (int i = 0; i < K; ++i) {
            float c = (float)(i - K / 2);
            g[i] = expf(-c * c * inv2s2);
            s += g[i];
        }
#pragma unroll
        for (int i = 0; i < K; ++i)
            g[i] = __int_as_float(__builtin_amdgcn_readfirstlane(__float_as_int(g[i] / s)));
    }

    // R5 addressing: per-lane 64-bit base pointers (proven fastest)
    const float* src0 = pred + (size_t)plane * H * W + gc0;
    const float* src1 = targ + (size_t)plane * H * W + gc0;

    auto loadrow = [&](int s, int y) -> float {
        float v = 0.f;
        if (iva && (unsigned)y < (unsigned)H)
            v = (s == 0 ? src0 : src1)[(long)y << 9];
        return v;
    };

    // Rotating accumulators (constant-indexed after the D-unroll)
    float mn[2][D], msq[2][D], m3a[2][D], m4a[2][D], xr[2][DX];
    float pfbuf[2][P];                        // deep prefetch ring
    float featp[4];
    float sums[4] = {0.f, 0.f, 0.f, 0.f};

#pragma unroll
    for (int j = 0; j < P; ++j) {             // warmup: rows y0 .. y0+P-1
        pfbuf[0][j] = loadrow(0, y0 + j);
        pfbuf[1][j] = loadrow(1, y0 + j);
    }

    if constexpr (TAILSPLIT) {
        for (int yy = 0; yy < TMAIN; yy += D) {
#pragma unroll
            for (int u = 0; u < D; ++u) {
                STAT_ITER(yy + u, u)          // i % D == u (D | yy)
            }
        }
        if constexpr (TTAIL > 0) {
#pragma unroll
            for (int u = 0; u < TTAIL; ++u) {
                STAT_ITER(TMAIN + u, u)       // TMAIN % D == 0
            }
        }
    } else {
        for (int yy = 0; yy < Tp; yy += D) {
#pragma unroll
            for (int u = 0; u < D; ++u) {
                STAT_ITER(yy + u, u)
            }
        }
    }

    // per-wave reduction, then one cross-wave LDS pass, 4 atomics per block
    __shared__ float red[4][4];   // [wave][feature]
#pragma unroll
    for (int f = 0; f < 4; ++f) {
        float v = sums[f] * emask;
#pragma unroll
        for (int off = 32; off > 0; off >>= 1) v += __shfl_down(v, off, 64);
        if (t == 0) red[wv][f] = v;
    }
    __syncthreads();
    if (threadIdx.x < 4) {
        float v = red[0][threadIdx.x] + red[1][threadIdx.x]
                + red[2][threadIdx.x] + red[3][threadIdx.x];
        atomicAdd(&acc[threadIdx.x], (double)v);
    }
}

extern "C" void kernel_launch(void* const* d_in, const int* in_sizes, int n_in,
                              void* d_out, int out_size, void* d_ws, size_t ws_size,
                              hipStream_t stream) {
    const float* pred = (const float*)d_in[0];
    const float* targ = (const float*)d_in[1];
    double* acc = (double*)d_ws;
    float* out = (float*)d_out;

    init_acc_kernel<<<1, 64, 0, stream>>>(acc);

    // K, BAND, D, DX(|D, >R), P(|D), NSTRIP, TAILSPLIT; 4 waves/block
    // K=3: literal R5 config.
    // K=5: literal R5 config (padded loop, 2 dead iters — tail-split regressed it in R8).
    // K=7: literal R8 config (BAND=32, tail-split, P=5 — measured 188us).
    stat_kernel<3, 32,  4, 2, 4,  9, 0><<<dim3(PLANES *  9 * 16 / 4), 256, 0, stream>>>(pred, targ, acc);
    stat_kernel<5, 32,  7, 7, 7, 10, 0><<<dim3(PLANES * 10 * 16 / 4), 256, 0, stream>>>(pred, targ, acc);
    stat_kernel<7, 32, 10, 5, 5, 10, 1><<<dim3(PLANES * 10 * 16 / 4), 256, 0, stream>>>(pred, targ, acc);

    final_kernel<<<1, 64, 0, stream>>>(acc, out);
}